// Round 1
// baseline (2005.666 us; speedup 1.0000x reference)
//
#include <hip/hip_runtime.h>
#include <cstdint>
#include <cstddef>

#define BN_EPS 1e-5f
#define SCAN_T 256
#define SCAN_CHUNK 1024

// ---------------- BN: per-block partial sums (no atomics) ----------------
__global__ void k_stats(const float* __restrict__ X, const float* __restrict__ imp,
                        float* __restrict__ ps, float* __restrict__ pq, int n) {
    const int c = threadIdx.x;           // 0..127 = channel
    float s = 0.f, q = 0.f;
    for (int r = blockIdx.x; r < n; r += gridDim.x) {
        float v = X[(size_t)r * 128 + c] * imp[r];
        s += v; q += v * v;
    }
    ps[blockIdx.x * 128 + c] = s;
    pq[blockIdx.x * 128 + c] = q;
}

__global__ void k_finalize(const float* __restrict__ ps, const float* __restrict__ pq,
                           const float* __restrict__ gamma, const float* __restrict__ beta,
                           float* __restrict__ scale, float* __restrict__ shift,
                           int nblocks, float inv_n) {
    const int c = threadIdx.x;           // 128 threads
    float s = 0.f, q = 0.f;
    for (int b = 0; b < nblocks; ++b) { s += ps[b * 128 + c]; q += pq[b * 128 + c]; }
    float mu  = s * inv_n;
    float var = fmaf(-mu, mu, q * inv_n);   // biased variance
    float rs  = rsqrtf(var + BN_EPS);
    float sc  = gamma[c] * rs;
    scale[c] = sc;
    shift[c] = fmaf(-mu, sc, beta[c]);
}

__global__ void k_bn(const float* __restrict__ X, const float* __restrict__ imp,
                     const float* __restrict__ scale, const float* __restrict__ shift,
                     float* __restrict__ h0, int n) {
    int g = blockIdx.x * blockDim.x + threadIdx.x;
    const int stride = gridDim.x * blockDim.x;
    const int total = n * 32;            // groups of 4 channels
    for (; g < total; g += stride) {
        int row = g >> 5;
        int c4  = (g & 31) << 2;
        float im = imp[row];
        const float4 x  = *reinterpret_cast<const float4*>(X + (size_t)row * 128 + c4);
        const float4 sc = *reinterpret_cast<const float4*>(scale + c4);
        const float4 sh = *reinterpret_cast<const float4*>(shift + c4);
        float4 y;
        y.x = fmaf(x.x * im, sc.x, sh.x);
        y.y = fmaf(x.y * im, sc.y, sh.y);
        y.z = fmaf(x.z * im, sc.z, sh.z);
        y.w = fmaf(x.w * im, sc.w, sh.w);
        *reinterpret_cast<float4*>(h0 + (size_t)row * 128 + c4) = y;
    }
}

// ---------------- CSR-by-destination build ----------------
__global__ void k_hist(const int* __restrict__ dst, int* __restrict__ deg, int e) {
    int i = blockIdx.x * blockDim.x + threadIdx.x;
    const int stride = gridDim.x * blockDim.x;
    for (; i < e; i += stride) atomicAdd(&deg[dst[i]], 1);
}

__global__ void k_chunk_sum(const int* __restrict__ deg, int* __restrict__ part, int n) {
    __shared__ int sm[SCAN_T];
    const int t = threadIdx.x;
    const int base = blockIdx.x * SCAN_CHUNK + t * 4;
    int s = 0;
#pragma unroll
    for (int j = 0; j < 4; ++j) { int idx = base + j; if (idx < n) s += deg[idx]; }
    sm[t] = s;
    __syncthreads();
    for (int off = SCAN_T / 2; off > 0; off >>= 1) {
        if (t < off) sm[t] += sm[t + off];
        __syncthreads();
    }
    if (t == 0) part[blockIdx.x] = sm[0];
}

// exclusive scan of the (<=128) chunk partials; writes total into *total_out
__global__ void k_scan_part(int* __restrict__ part, int nparts, int* __restrict__ total_out) {
    __shared__ int sm[128];
    const int t = threadIdx.x;          // 128 threads
    int v = (t < nparts) ? part[t] : 0;
    const int mys = v;
    sm[t] = v;
    __syncthreads();
    for (int off = 1; off < 128; off <<= 1) {
        int u = (t >= off) ? sm[t - off] : 0;
        __syncthreads();
        sm[t] += u;
        __syncthreads();
    }
    if (t < nparts) part[t] = sm[t] - mys;
    if (t == 127) *total_out = sm[127];
}

__global__ void k_chunk_scan(const int* __restrict__ deg, const int* __restrict__ part,
                             int* __restrict__ rowptr, int* __restrict__ cursor, int n) {
    __shared__ int sm[SCAN_T];
    const int t = threadIdx.x;
    const int base = blockIdx.x * SCAN_CHUNK + t * 4;
    int l[4];
    int s = 0;
#pragma unroll
    for (int j = 0; j < 4; ++j) { int idx = base + j; l[j] = (idx < n) ? deg[idx] : 0; s += l[j]; }
    const int mys = s;
    sm[t] = s;
    __syncthreads();
    for (int off = 1; off < SCAN_T; off <<= 1) {
        int u = (t >= off) ? sm[t - off] : 0;
        __syncthreads();
        sm[t] += u;
        __syncthreads();
    }
    int excl = sm[t] - mys + part[blockIdx.x];
#pragma unroll
    for (int j = 0; j < 4; ++j) {
        int idx = base + j;
        if (idx < n) { rowptr[idx] = excl; cursor[idx] = excl; excl += l[j]; }
    }
}

__global__ void k_scatter(const int* __restrict__ src, const int* __restrict__ dst,
                          int* __restrict__ cursor, int* __restrict__ csr, int e) {
    int i = blockIdx.x * blockDim.x + threadIdx.x;
    const int stride = gridDim.x * blockDim.x;
    for (; i < e; i += stride) {
        int p = atomicAdd(&cursor[dst[i]], 1);
        csr[p] = src[i];
    }
}

// ---------------- Fused GIN layer: agg + (h+agg)@W + b, tanh ----------------
// One wave (64 lanes) per node. lane = input channel (k) during aggregation,
// lane = output channel (j) during the matvec (row broadcast via __shfl).
template <int D_IN, bool HAS_AGG, bool HAS_BIAS>
__global__ void k_gin(const float* __restrict__ hin, int in_stride,
                      float* __restrict__ hout, int out_stride,
                      const float* __restrict__ W, const float* __restrict__ bias,
                      const int* __restrict__ rowptr, const int* __restrict__ csr,
                      int n) {
    constexpr int KREG = D_IN / 64;
    __shared__ float Wl[D_IN * 64];
    for (int t = threadIdx.x; t < D_IN * 64; t += blockDim.x) Wl[t] = W[t];
    __syncthreads();

    const int lane = threadIdx.x & 63;
    const int nw = blockDim.x >> 6;
    int w = blockIdx.x * nw + (threadIdx.x >> 6);
    const int wstep = gridDim.x * nw;

    for (; w < n; w += wstep) {
        float acc[KREG];
#pragma unroll
        for (int r = 0; r < KREG; ++r)
            acc[r] = hin[(size_t)w * in_stride + r * 64 + lane];

        if (HAS_AGG) {
            const int beg = rowptr[w], end = rowptr[w + 1];
            for (int base = beg; base < end; base += 64) {
                int cnt = end - base; if (cnt > 64) cnt = 64;
                int myidx = (lane < cnt) ? csr[base + lane] : 0;
                for (int j = 0; j < cnt; ++j) {
                    int sidx = __shfl(myidx, j);
                    const float* row = hin + (size_t)sidx * in_stride;
#pragma unroll
                    for (int r = 0; r < KREG; ++r)
                        acc[r] += row[r * 64 + lane];
                }
            }
        }

        float o0 = HAS_BIAS ? bias[lane] : 0.f;
        float o1 = 0.f;
#pragma unroll
        for (int r = 0; r < KREG; ++r) {
#pragma unroll
            for (int k = 0; k < 64; k += 2) {
                float a0 = __shfl(acc[r], k);
                float a1 = __shfl(acc[r], k + 1);
                o0 = fmaf(a0, Wl[(r * 64 + k) * 64 + lane], o0);
                o1 = fmaf(a1, Wl[(r * 64 + k + 1) * 64 + lane], o1);
            }
        }
        hout[(size_t)w * out_stride + lane] = tanhf(o0 + o1);
    }
}

// ---------------- launch ----------------
extern "C" void kernel_launch(void* const* d_in, const int* in_sizes, int n_in,
                              void* d_out, int out_size, void* d_ws, size_t ws_size,
                              hipStream_t stream) {
    const float* X     = (const float*)d_in[0];
    const float* imp   = (const float*)d_in[1];
    const int*   ei    = (const int*)d_in[2];
    const float* gamma = (const float*)d_in[3];
    const float* beta  = (const float*)d_in[4];
    const float* W1 = (const float*)d_in[5];
    const float* b1 = (const float*)d_in[6];
    const float* W2 = (const float*)d_in[7];
    const float* b2 = (const float*)d_in[8];
    const float* W3 = (const float*)d_in[9];
    const float* b3 = (const float*)d_in[10];
    const float* W4 = (const float*)d_in[11];
    const float* b4 = (const float*)d_in[12];
    const float* W5 = (const float*)d_in[13];
    const float* b5 = (const float*)d_in[14];
    const float* Wf = (const float*)d_in[15];
    float* out = (float*)d_out;

    const int n = in_sizes[1];        // N (X_importance flat count)
    const int e = in_sizes[2] / 2;    // E
    const int* src = ei;
    const int* dst = ei + e;

    // workspace carve (256B aligned regions)
    char* p = (char*)d_ws;
    auto carve = [&](size_t bytes) { char* r = p; p += (bytes + 255) & ~(size_t)255; return r; };
    float* h0     = (float*)carve((size_t)n * 128 * sizeof(float));
    int*   deg    = (int*)carve((size_t)n * sizeof(int));
    int*   rowptr = (int*)carve((size_t)(n + 1) * sizeof(int));
    int*   cursor = (int*)carve((size_t)n * sizeof(int));
    int*   csr    = (int*)carve((size_t)e * sizeof(int));
    const int nchunks = (n + SCAN_CHUNK - 1) / SCAN_CHUNK;   // <=128 for n<=131072
    int*   part   = (int*)carve((size_t)nchunks * sizeof(int));
    const int STATS_B = 256;
    float* ps    = (float*)carve((size_t)STATS_B * 128 * sizeof(float));
    float* pq    = (float*)carve((size_t)STATS_B * 128 * sizeof(float));
    float* scale = (float*)carve(128 * sizeof(float));
    float* shift = (float*)carve(128 * sizeof(float));

    // BN (batch statistics)
    k_stats<<<STATS_B, 128, 0, stream>>>(X, imp, ps, pq, n);
    k_finalize<<<1, 128, 0, stream>>>(ps, pq, gamma, beta, scale, shift, STATS_B, 1.0f / (float)n);
    k_bn<<<2048, 256, 0, stream>>>(X, imp, scale, shift, h0, n);

    // CSR build (by destination), reused by all 5 conv layers
    hipMemsetAsync(deg, 0, (size_t)n * sizeof(int), stream);
    k_hist<<<1024, 256, 0, stream>>>(dst, deg, e);
    k_chunk_sum<<<nchunks, SCAN_T, 0, stream>>>(deg, part, n);
    k_scan_part<<<1, 128, 0, stream>>>(part, nchunks, rowptr + n);
    k_chunk_scan<<<nchunks, SCAN_T, 0, stream>>>(deg, part, rowptr, cursor, n);
    k_scatter<<<1024, 256, 0, stream>>>(src, dst, cursor, csr, e);

    // GIN layers: outputs land directly in their concat column slices of d_out
    k_gin<128, true, true ><<<2048, 256, 0, stream>>>(h0,        128, out + 0,   384, W1, b1, rowptr, csr, n);
    k_gin< 64, true, true ><<<2048, 256, 0, stream>>>(out + 0,   384, out + 64,  384, W2, b2, rowptr, csr, n);
    k_gin< 64, true, true ><<<2048, 256, 0, stream>>>(out + 64,  384, out + 128, 384, W3, b3, rowptr, csr, n);
    k_gin< 64, true, true ><<<2048, 256, 0, stream>>>(out + 128, 384, out + 192, 384, W4, b4, rowptr, csr, n);
    k_gin< 64, true, true ><<<2048, 256, 0, stream>>>(out + 192, 384, out + 256, 384, W5, b5, rowptr, csr, n);
    k_gin< 64, false, false><<<2048, 256, 0, stream>>>(out + 256, 384, out + 320, 384, Wf, nullptr, rowptr, csr, n);
}

// Round 2
// 1572.587 us; speedup vs baseline: 1.2754x; 1.2754x over previous
//
#include <hip/hip_runtime.h>
#include <cstdint>
#include <cstddef>

#define BN_EPS 1e-5f
#define SCAN_T 256
#define SCAN_CHUNK 1024

// ---------------- BN: per-block partial sums (no atomics) ----------------
__global__ void k_stats(const float* __restrict__ X, const float* __restrict__ imp,
                        float* __restrict__ ps, float* __restrict__ pq, int n) {
    const int c = threadIdx.x;           // 0..127 = channel
    float s = 0.f, q = 0.f;
    for (int r = blockIdx.x; r < n; r += gridDim.x) {
        float v = X[(size_t)r * 128 + c] * imp[r];
        s += v; q += v * v;
    }
    ps[blockIdx.x * 128 + c] = s;
    pq[blockIdx.x * 128 + c] = q;
}

__global__ void k_finalize(const float* __restrict__ ps, const float* __restrict__ pq,
                           const float* __restrict__ gamma, const float* __restrict__ beta,
                           float* __restrict__ scale, float* __restrict__ shift,
                           int nblocks, float inv_n) {
    const int c = threadIdx.x;           // 128 threads
    float s = 0.f, q = 0.f;
    for (int b = 0; b < nblocks; ++b) { s += ps[b * 128 + c]; q += pq[b * 128 + c]; }
    float mu  = s * inv_n;
    float var = fmaf(-mu, mu, q * inv_n);   // biased variance
    float rs  = rsqrtf(var + BN_EPS);
    float sc  = gamma[c] * rs;
    scale[c] = sc;
    shift[c] = fmaf(-mu, sc, beta[c]);
}

__global__ void k_bn(const float* __restrict__ X, const float* __restrict__ imp,
                     const float* __restrict__ scale, const float* __restrict__ shift,
                     float* __restrict__ h0, int n) {
    int g = blockIdx.x * blockDim.x + threadIdx.x;
    const int stride = gridDim.x * blockDim.x;
    const int total = n * 32;            // groups of 4 channels
    for (; g < total; g += stride) {
        int row = g >> 5;
        int c4  = (g & 31) << 2;
        float im = imp[row];
        const float4 x  = *reinterpret_cast<const float4*>(X + (size_t)row * 128 + c4);
        const float4 sc = *reinterpret_cast<const float4*>(scale + c4);
        const float4 sh = *reinterpret_cast<const float4*>(shift + c4);
        float4 y;
        y.x = fmaf(x.x * im, sc.x, sh.x);
        y.y = fmaf(x.y * im, sc.y, sh.y);
        y.z = fmaf(x.z * im, sc.z, sh.z);
        y.w = fmaf(x.w * im, sc.w, sh.w);
        *reinterpret_cast<float4*>(h0 + (size_t)row * 128 + c4) = y;
    }
}

// ---------------- CSR-by-destination build ----------------
__global__ void k_hist(const int* __restrict__ dst, int* __restrict__ deg, int e) {
    int i = blockIdx.x * blockDim.x + threadIdx.x;
    const int stride = gridDim.x * blockDim.x;
    for (; i < e; i += stride) atomicAdd(&deg[dst[i]], 1);
}

__global__ void k_chunk_sum(const int* __restrict__ deg, int* __restrict__ part, int n) {
    __shared__ int sm[SCAN_T];
    const int t = threadIdx.x;
    const int base = blockIdx.x * SCAN_CHUNK + t * 4;
    int s = 0;
#pragma unroll
    for (int j = 0; j < 4; ++j) { int idx = base + j; if (idx < n) s += deg[idx]; }
    sm[t] = s;
    __syncthreads();
    for (int off = SCAN_T / 2; off > 0; off >>= 1) {
        if (t < off) sm[t] += sm[t + off];
        __syncthreads();
    }
    if (t == 0) part[blockIdx.x] = sm[0];
}

// exclusive scan of the (<=128) chunk partials; writes total into *total_out
__global__ void k_scan_part(int* __restrict__ part, int nparts, int* __restrict__ total_out) {
    __shared__ int sm[128];
    const int t = threadIdx.x;          // 128 threads
    int v = (t < nparts) ? part[t] : 0;
    const int mys = v;
    sm[t] = v;
    __syncthreads();
    for (int off = 1; off < 128; off <<= 1) {
        int u = (t >= off) ? sm[t - off] : 0;
        __syncthreads();
        sm[t] += u;
        __syncthreads();
    }
    if (t < nparts) part[t] = sm[t] - mys;
    if (t == 127) *total_out = sm[127];
}

__global__ void k_chunk_scan(const int* __restrict__ deg, const int* __restrict__ part,
                             int* __restrict__ rowptr, int* __restrict__ cursor, int n) {
    __shared__ int sm[SCAN_T];
    const int t = threadIdx.x;
    const int base = blockIdx.x * SCAN_CHUNK + t * 4;
    int l[4];
    int s = 0;
#pragma unroll
    for (int j = 0; j < 4; ++j) { int idx = base + j; l[j] = (idx < n) ? deg[idx] : 0; s += l[j]; }
    const int mys = s;
    sm[t] = s;
    __syncthreads();
    for (int off = 1; off < SCAN_T; off <<= 1) {
        int u = (t >= off) ? sm[t - off] : 0;
        __syncthreads();
        sm[t] += u;
        __syncthreads();
    }
    int excl = sm[t] - mys + part[blockIdx.x];
#pragma unroll
    for (int j = 0; j < 4; ++j) {
        int idx = base + j;
        if (idx < n) { rowptr[idx] = excl; cursor[idx] = excl; excl += l[j]; }
    }
}

__global__ void k_scatter(const int* __restrict__ src, const int* __restrict__ dst,
                          int* __restrict__ cursor, int* __restrict__ csr, int e) {
    int i = blockIdx.x * blockDim.x + threadIdx.x;
    const int stride = gridDim.x * blockDim.x;
    for (; i < e; i += stride) {
        int p = atomicAdd(&cursor[dst[i]], 1);
        csr[p] = src[i];
    }
}

// ---------------- Fused GIN layer ----------------
// One wave per node. Wave split into 4 groups x 16 lanes: each group handles a
// different edge; each lane loads a float4 (16 lanes x 16B = full 64-float row)
// -> ~16 independent dwordx4 loads in flight per wave (unroll 4).
// Channel layout during agg: a[r*4+c] = channel r*64 + glane*4 + c.
// Partial sums across groups combined with 2 shfl_xor butterflies.
// GEMM: lane = output channel j; a_k broadcast via __shfl from lane (k%64)/4.
// FUSE_FC: apply the final bias-free fc + tanh in the epilogue (input = val in regs).
template <int D_IN, bool HAS_AGG, bool FUSE_FC>
__global__ __launch_bounds__(256) void k_gin(
        const float* __restrict__ hin, int in_stride,
        float* __restrict__ hout, int out_stride,
        float* __restrict__ hcomp,
        const float* __restrict__ W, const float* __restrict__ bias,
        const float* __restrict__ Wfc,
        const int* __restrict__ rowptr, const int* __restrict__ csr, int n) {
    constexpr int V = D_IN / 64;
    __shared__ float Wl[D_IN * 64 + (FUSE_FC ? 64 * 64 : 0)];
    for (int t = threadIdx.x; t < D_IN * 64; t += blockDim.x) Wl[t] = W[t];
    if (FUSE_FC)
        for (int t = threadIdx.x; t < 64 * 64; t += blockDim.x) Wl[D_IN * 64 + t] = Wfc[t];
    __syncthreads();

    const int lane  = threadIdx.x & 63;
    const int glane = lane & 15;
    const int grp   = lane >> 4;
    const int nw = blockDim.x >> 6;
    int w = blockIdx.x * nw + (threadIdx.x >> 6);
    const int wstep = gridDim.x * nw;

    for (; w < n; w += wstep) {
        float a[V * 4];
        {
            const float* self = hin + (size_t)w * in_stride;
#pragma unroll
            for (int r = 0; r < V; ++r) {
                float4 s = make_float4(0.f, 0.f, 0.f, 0.f);
                if (grp == 0)
                    s = *reinterpret_cast<const float4*>(self + r * 64 + glane * 4);
                a[r * 4 + 0] = s.x; a[r * 4 + 1] = s.y;
                a[r * 4 + 2] = s.z; a[r * 4 + 3] = s.w;
            }
        }

        if (HAS_AGG) {
            const int beg = rowptr[w], end = rowptr[w + 1];
            for (int base = beg; base < end; base += 64) {
                int cnt = end - base; if (cnt > 64) cnt = 64;
                const int myidx = (lane < cnt) ? csr[base + lane] : 0;
                const int jmax = (cnt + 3) >> 2;
#pragma unroll 4
                for (int j = 0; j < jmax; ++j) {
                    const int ej = (j << 2) + grp;
                    const bool valid = (ej < cnt);
                    const int sidx = __shfl(myidx, ej);   // 0 when ej >= cnt (safe)
                    const float* row = hin + (size_t)sidx * in_stride;
#pragma unroll
                    for (int r = 0; r < V; ++r) {
                        const float4 v = *reinterpret_cast<const float4*>(row + r * 64 + glane * 4);
                        if (valid) {
                            a[r * 4 + 0] += v.x; a[r * 4 + 1] += v.y;
                            a[r * 4 + 2] += v.z; a[r * 4 + 3] += v.w;
                        }
                    }
                }
            }
            // combine the 4 per-group partial sums (also replicates to all lanes)
#pragma unroll
            for (int c = 0; c < V * 4; ++c) {
                a[c] += __shfl_xor(a[c], 16);
                a[c] += __shfl_xor(a[c], 32);
            }
        }
        // (!HAS_AGG: values live in lanes 0..15, which is all the GEMM shfl reads)

        float o0 = bias ? bias[lane] : 0.f;
        float o1 = 0.f;
#pragma unroll
        for (int k = 0; k < D_IN; k += 2) {
            const float a0 = __shfl(a[((k >> 6) << 2) + (k & 3)], (k & 63) >> 2);
            const float a1 = __shfl(a[(((k + 1) >> 6) << 2) + ((k + 1) & 3)], ((k + 1) & 63) >> 2);
            o0 = fmaf(a0, Wl[k * 64 + lane], o0);
            o1 = fmaf(a1, Wl[(k + 1) * 64 + lane], o1);
        }
        const float val = tanhf(o0 + o1);
        hout[(size_t)w * out_stride + lane] = val;
        if (FUSE_FC) {
            const float* W2 = Wl + D_IN * 64;
            float f0 = 0.f, f1 = 0.f;
#pragma unroll
            for (int k = 0; k < 64; k += 2) {
                f0 = fmaf(__shfl(val, k),     W2[k * 64 + lane],       f0);
                f1 = fmaf(__shfl(val, k + 1), W2[(k + 1) * 64 + lane], f1);
            }
            hout[(size_t)w * out_stride + 64 + lane] = tanhf(f0 + f1);
        } else if (hcomp) {
            hcomp[(size_t)w * 64 + lane] = val;
        }
    }
}

// ---------------- launch ----------------
extern "C" void kernel_launch(void* const* d_in, const int* in_sizes, int n_in,
                              void* d_out, int out_size, void* d_ws, size_t ws_size,
                              hipStream_t stream) {
    const float* X     = (const float*)d_in[0];
    const float* imp   = (const float*)d_in[1];
    const int*   ei    = (const int*)d_in[2];
    const float* gamma = (const float*)d_in[3];
    const float* beta  = (const float*)d_in[4];
    const float* W1 = (const float*)d_in[5];
    const float* b1 = (const float*)d_in[6];
    const float* W2 = (const float*)d_in[7];
    const float* b2 = (const float*)d_in[8];
    const float* W3 = (const float*)d_in[9];
    const float* b3 = (const float*)d_in[10];
    const float* W4 = (const float*)d_in[11];
    const float* b4 = (const float*)d_in[12];
    const float* W5 = (const float*)d_in[13];
    const float* b5 = (const float*)d_in[14];
    const float* Wf = (const float*)d_in[15];
    float* out = (float*)d_out;

    const int n = in_sizes[1];        // N
    const int e = in_sizes[2] / 2;    // E
    const int* src = ei;
    const int* dst = ei + e;

    // workspace carve (256B aligned regions)
    char* p = (char*)d_ws;
    auto carve = [&](size_t bytes) { char* r = p; p += (bytes + 255) & ~(size_t)255; return r; };
    float* h0     = (float*)carve((size_t)n * 128 * sizeof(float));
    int*   deg    = (int*)carve((size_t)n * sizeof(int));
    int*   rowptr = (int*)carve((size_t)(n + 1) * sizeof(int));
    int*   cursor = (int*)carve((size_t)n * sizeof(int));
    int*   csr    = (int*)carve((size_t)e * sizeof(int));
    const int nchunks = (n + SCAN_CHUNK - 1) / SCAN_CHUNK;
    int*   part   = (int*)carve((size_t)nchunks * sizeof(int));
    const int STATS_B = 256;
    float* ps    = (float*)carve((size_t)STATS_B * 128 * sizeof(float));
    float* pq    = (float*)carve((size_t)STATS_B * 128 * sizeof(float));
    float* scale = (float*)carve(128 * sizeof(float));
    float* shift = (float*)carve(128 * sizeof(float));
    // compact ping-pong activation buffers [N,64] (gather locality)
    const size_t comp_bytes = ((size_t)n * 64 * sizeof(float) + 255) & ~(size_t)255;
    const bool use_comp = ((size_t)(p - (char*)d_ws) + 2 * comp_bytes) <= ws_size;
    float* hcA = use_comp ? (float*)carve(comp_bytes) : nullptr;
    float* hcB = use_comp ? (float*)carve(comp_bytes) : nullptr;

    // BN (batch statistics)
    k_stats<<<STATS_B, 128, 0, stream>>>(X, imp, ps, pq, n);
    k_finalize<<<1, 128, 0, stream>>>(ps, pq, gamma, beta, scale, shift, STATS_B, 1.0f / (float)n);
    k_bn<<<2048, 256, 0, stream>>>(X, imp, scale, shift, h0, n);

    // CSR build (by destination), reused by all 5 conv layers
    hipMemsetAsync(deg, 0, (size_t)n * sizeof(int), stream);
    k_hist<<<1024, 256, 0, stream>>>(dst, deg, e);
    k_chunk_sum<<<nchunks, SCAN_T, 0, stream>>>(deg, part, n);
    k_scan_part<<<1, 128, 0, stream>>>(part, nchunks, rowptr + n);
    k_chunk_scan<<<nchunks, SCAN_T, 0, stream>>>(deg, part, rowptr, cursor, n);
    k_scatter<<<1024, 256, 0, stream>>>(src, dst, cursor, csr, e);

    const int GB = 8192;   // gin grid
    if (use_comp) {
        k_gin<128, true,  false><<<GB, 256, 0, stream>>>(h0, 128, out + 0,   384, hcA,     W1, b1, nullptr, rowptr, csr, n);
        k_gin< 64, true,  false><<<GB, 256, 0, stream>>>(hcA, 64, out + 64,  384, hcB,     W2, b2, nullptr, rowptr, csr, n);
        k_gin< 64, true,  false><<<GB, 256, 0, stream>>>(hcB, 64, out + 128, 384, hcA,     W3, b3, nullptr, rowptr, csr, n);
        k_gin< 64, true,  false><<<GB, 256, 0, stream>>>(hcA, 64, out + 192, 384, hcB,     W4, b4, nullptr, rowptr, csr, n);
        k_gin< 64, true,  true ><<<GB, 256, 0, stream>>>(hcB, 64, out + 256, 384, nullptr, W5, b5, Wf,      rowptr, csr, n);
    } else {
        k_gin<128, true,  false><<<GB, 256, 0, stream>>>(h0, 128,       out + 0,   384, nullptr, W1, b1, nullptr, rowptr, csr, n);
        k_gin< 64, true,  false><<<GB, 256, 0, stream>>>(out + 0,   384, out + 64,  384, nullptr, W2, b2, nullptr, rowptr, csr, n);
        k_gin< 64, true,  false><<<GB, 256, 0, stream>>>(out + 64,  384, out + 128, 384, nullptr, W3, b3, nullptr, rowptr, csr, n);
        k_gin< 64, true,  false><<<GB, 256, 0, stream>>>(out + 128, 384, out + 192, 384, nullptr, W4, b4, nullptr, rowptr, csr, n);
        k_gin< 64, true,  true ><<<GB, 256, 0, stream>>>(out + 192, 384, out + 256, 384, nullptr, W5, b5, Wf,      rowptr, csr, n);
    }
}